// Round 8
// baseline (19374.034 us; speedup 1.0000x reference)
//
#include <hip/hip_runtime.h>

// Echo State Network, T=1024 sequential steps of r' = 0.5 r + 0.5 tanh(W r + Win u).
// Persistent kernel. W pinned in hard-named AGPRs (verified r4: VGPR_Count=128).
//
// r8 design. Sync skeleton = r5 (proven 4.09 ms, deterministic absmax 6.1e-5):
//   waves 4-5 poll 128 flag-pairs -> barrier -> stage -> barrier A -> matvec ->
//   paired 8B atomic publish -> barrier B (vmcnt drain) -> tid0 flag store.
// Change vs r5: STAGING is now ONE acquire-agent fence (flash L1/L2 inv, once
// per step — r4's disaster was an inv per POLL-ITERATION) + plain CACHED float4
// loads, instead of 2048x8B uncached atomic loads per WG. Payload becomes
// line-granular and L2-shared across the 32 WGs of an XCD (~4 MB -> ~0.1 MB of
// fabric traffic per step). Values stable while read (flag>=t gates rewrite),
// so no tearing. Producers keep atomic stores (punch through to L3).
// Pred = r6's psum split (off critical path; r6 was absmax-clean).
// r7's all-thread poll topology reverted (16x hot-line contention, regressed).
//
// RACE DETECTOR: absmax must read exactly 6.103516e-05 (deterministic value of
// rounds 1-6). Any other value => nondeterminism crept in.
//
// d_ws layout: [0, 32768): float rbuf[2][4096] (double-buffered r, 8B-paired rows)
//              [32768, 33792): int flags[256]  (last published step per WG)

#define T_STEPS 1024
#define R_DIM   4096
#define N_WG    256
#define N_THR   512
#define ROWS_PER_WG 16
#define K_CHUNKS 16          // R_DIM / (64 lanes * 4 floats)

#define AGENT __HIP_MEMORY_SCOPE_AGENT

typedef unsigned long long ull;
typedef unsigned int uint32;

__device__ __forceinline__ float fast_tanh(float x) {
    float ax = fabsf(x);
    float e  = __expf(-2.0f * ax);
    float t  = (1.0f - e) / (1.0f + e);
    return copysignf(t, x);
}

// Store one float4 into four named physical AGPRs.
#define WST4(A0, A1, A2, A3, vec)                                              \
    asm volatile("v_accvgpr_write_b32 a" #A0 ", %0\n\t"                        \
                 "v_accvgpr_write_b32 a" #A1 ", %1\n\t"                        \
                 "v_accvgpr_write_b32 a" #A2 ", %2\n\t"                        \
                 "v_accvgpr_write_b32 a" #A3 ", %3"                            \
                 :: "v"((vec).x), "v"((vec).y), "v"((vec).z), "v"((vec).w)     \
                 : "a" #A0, "a" #A1, "a" #A2, "a" #A3)

// One K-chunk of the two-row matvec: read 4+4 W values from AGPRs, FMA with rv.
#define MV2(c, A0, A1, A2, A3, B0, B1, B2, B3)                                 \
    do {                                                                       \
        float4 rv = rv4[(c) * 64 + lane];                                      \
        float w0, w1, w2, w3, u0, u1, u2, u3;                                  \
        asm volatile("v_accvgpr_read_b32 %0, a" #A0 "\n\t"                     \
                     "v_accvgpr_read_b32 %1, a" #A1 "\n\t"                     \
                     "v_accvgpr_read_b32 %2, a" #A2 "\n\t"                     \
                     "v_accvgpr_read_b32 %3, a" #A3 "\n\t"                     \
                     "v_accvgpr_read_b32 %4, a" #B0 "\n\t"                     \
                     "v_accvgpr_read_b32 %5, a" #B1 "\n\t"                     \
                     "v_accvgpr_read_b32 %6, a" #B2 "\n\t"                     \
                     "v_accvgpr_read_b32 %7, a" #B3                            \
                     : "=v"(w0), "=v"(w1), "=v"(w2), "=v"(w3),                 \
                       "=v"(u0), "=v"(u1), "=v"(u2), "=v"(u3));                \
        accA.x = fmaf(w0, rv.x, accA.x);                                       \
        accA.y = fmaf(w1, rv.y, accA.y);                                       \
        accA.z = fmaf(w2, rv.z, accA.z);                                       \
        accA.w = fmaf(w3, rv.w, accA.w);                                       \
        accB.x = fmaf(u0, rv.x, accB.x);                                       \
        accB.y = fmaf(u1, rv.y, accB.y);                                       \
        accB.z = fmaf(u2, rv.z, accB.z);                                       \
        accB.w = fmaf(u3, rv.w, accB.w);                                       \
    } while (0)

__global__ __launch_bounds__(N_THR, 2)
void esn_persistent(const float* __restrict__ batch,
                    const float* __restrict__ Win,
                    const float* __restrict__ W,
                    const float* __restrict__ Wout,
                    float* __restrict__ out,
                    float* __restrict__ rbuf,
                    int*   __restrict__ flags)
{
    __shared__ __align__(16) float r_lds[R_DIM];   // current r(t)
    __shared__ float b_lds[T_STEPS];               // input sequence
    __shared__ float psum_lds[8];                  // WG0 pred partials

    const int tid  = threadIdx.x;
    const int wid  = blockIdx.x;
    const int wave = tid >> 6;
    const int lane = tid & 63;
    const int rowA = wid * ROWS_PER_WG + wave * 2; // this wave's two W rows
    const int rowB = rowA + 1;

    for (int i = tid; i < R_DIM; i += N_THR) r_lds[i] = 0.0f;   // r(0) = 0
    for (int i = tid; i < T_STEPS; i += N_THR) b_lds[i] = batch[i];

    // Pin W rows in physical AGPRs. Lane's chunk c covers k = c*256 + lane*4.
    {
        const float4* pA = reinterpret_cast<const float4*>(W + (size_t)rowA * R_DIM);
        const float4* pB = reinterpret_cast<const float4*>(W + (size_t)rowB * R_DIM);
        float4 v;
        v = pA[ 0 * 64 + lane]; WST4(  0,   1,   2,   3, v);
        v = pA[ 1 * 64 + lane]; WST4(  4,   5,   6,   7, v);
        v = pA[ 2 * 64 + lane]; WST4(  8,   9,  10,  11, v);
        v = pA[ 3 * 64 + lane]; WST4( 12,  13,  14,  15, v);
        v = pA[ 4 * 64 + lane]; WST4( 16,  17,  18,  19, v);
        v = pA[ 5 * 64 + lane]; WST4( 20,  21,  22,  23, v);
        v = pA[ 6 * 64 + lane]; WST4( 24,  25,  26,  27, v);
        v = pA[ 7 * 64 + lane]; WST4( 28,  29,  30,  31, v);
        v = pA[ 8 * 64 + lane]; WST4( 32,  33,  34,  35, v);
        v = pA[ 9 * 64 + lane]; WST4( 36,  37,  38,  39, v);
        v = pA[10 * 64 + lane]; WST4( 40,  41,  42,  43, v);
        v = pA[11 * 64 + lane]; WST4( 44,  45,  46,  47, v);
        v = pA[12 * 64 + lane]; WST4( 48,  49,  50,  51, v);
        v = pA[13 * 64 + lane]; WST4( 52,  53,  54,  55, v);
        v = pA[14 * 64 + lane]; WST4( 56,  57,  58,  59, v);
        v = pA[15 * 64 + lane]; WST4( 60,  61,  62,  63, v);
        v = pB[ 0 * 64 + lane]; WST4( 64,  65,  66,  67, v);
        v = pB[ 1 * 64 + lane]; WST4( 68,  69,  70,  71, v);
        v = pB[ 2 * 64 + lane]; WST4( 72,  73,  74,  75, v);
        v = pB[ 3 * 64 + lane]; WST4( 76,  77,  78,  79, v);
        v = pB[ 4 * 64 + lane]; WST4( 80,  81,  82,  83, v);
        v = pB[ 5 * 64 + lane]; WST4( 84,  85,  86,  87, v);
        v = pB[ 6 * 64 + lane]; WST4( 88,  89,  90,  91, v);
        v = pB[ 7 * 64 + lane]; WST4( 92,  93,  94,  95, v);
        v = pB[ 8 * 64 + lane]; WST4( 96,  97,  98,  99, v);
        v = pB[ 9 * 64 + lane]; WST4(100, 101, 102, 103, v);
        v = pB[10 * 64 + lane]; WST4(104, 105, 106, 107, v);
        v = pB[11 * 64 + lane]; WST4(108, 109, 110, 111, v);
        v = pB[12 * 64 + lane]; WST4(112, 113, 114, 115, v);
        v = pB[13 * 64 + lane]; WST4(116, 117, 118, 119, v);
        v = pB[14 * 64 + lane]; WST4(120, 121, 122, 123, v);
        v = pB[15 * 64 + lane]; WST4(124, 125, 126, 127, v);
    }
    const float winA0 = Win[2 * rowA], winA1 = Win[2 * rowA + 1];
    const float winB0 = Win[2 * rowB], winB1 = Win[2 * rowB + 1];

    __syncthreads();

    const float4* rv4 = reinterpret_cast<const float4*>(r_lds);
    float4* rl4 = reinterpret_cast<float4*>(r_lds);
    const ull* flags8 = reinterpret_cast<const ull*>(flags);

    for (int t = 0; t < T_STEPS; ++t) {
        if (t > 0) {
            // Waves 4-5 poll flag PAIRS (relaxed; 8 shared hot lines — r5 topology).
            if (tid >= 256 && tid < 256 + 128) {
                const ull* fp = flags8 + (tid - 256);
                for (;;) {
                    ull v = __hip_atomic_load(fp, __ATOMIC_RELAXED, AGENT);
                    if ((int)(uint32)v >= t && (int)(uint32)(v >> 32) >= t) break;
                    __builtin_amdgcn_s_sleep(1);
                }
            }
            __syncthreads();
            // ONE acquire fence per step: flash-invalidate stale L1/L2 lines,
            // then stage with plain CACHED float4 loads (L2-shared per XCD).
            __builtin_amdgcn_fence(__ATOMIC_ACQUIRE, "agent");
            const float4* src4 = reinterpret_cast<const float4*>(
                rbuf + (size_t)(t & 1) * R_DIM);
            float4 s0 = src4[tid];
            float4 s1 = src4[tid + 512];
            rl4[tid]       = s0;
            rl4[tid + 512] = s1;
            __syncthreads();   // barrier A: r(t) staged, all flags >= t seen by WG

            // Finalize pred[t-2] from last step's psums (WG0 tid0, off crit path).
            if (wid == 0 && tid == 0 && t >= 2) {
                float s = ((psum_lds[0] + psum_lds[1]) + (psum_lds[2] + psum_lds[3]))
                        + ((psum_lds[4] + psum_lds[5]) + (psum_lds[6] + psum_lds[7]));
                out[t - 2] = s + fmaf(Wout[1], b_lds[t - 2], Wout[0]);
            }
        }

        // y = W r(t) for this wave's two rows (W in AGPRs, r broadcast from LDS).
        float4 accA = make_float4(0.f, 0.f, 0.f, 0.f);
        float4 accB = make_float4(0.f, 0.f, 0.f, 0.f);
        MV2( 0,   0,   1,   2,   3,  64,  65,  66,  67);
        MV2( 1,   4,   5,   6,   7,  68,  69,  70,  71);
        MV2( 2,   8,   9,  10,  11,  72,  73,  74,  75);
        MV2( 3,  12,  13,  14,  15,  76,  77,  78,  79);
        MV2( 4,  16,  17,  18,  19,  80,  81,  82,  83);
        MV2( 5,  20,  21,  22,  23,  84,  85,  86,  87);
        MV2( 6,  24,  25,  26,  27,  88,  89,  90,  91);
        MV2( 7,  28,  29,  30,  31,  92,  93,  94,  95);
        MV2( 8,  32,  33,  34,  35,  96,  97,  98,  99);
        MV2( 9,  36,  37,  38,  39, 100, 101, 102, 103);
        MV2(10,  40,  41,  42,  43, 104, 105, 106, 107);
        MV2(11,  44,  45,  46,  47, 108, 109, 110, 111);
        MV2(12,  48,  49,  50,  51, 112, 113, 114, 115);
        MV2(13,  52,  53,  54,  55, 116, 117, 118, 119);
        MV2(14,  56,  57,  58,  59, 120, 121, 122, 123);
        MV2(15,  60,  61,  62,  63, 124, 125, 126, 127);

        float sA = (accA.x + accA.y) + (accA.z + accA.w);
        float sB = (accB.x + accB.y) + (accB.z + accB.w);
        #pragma unroll
        for (int m = 1; m < 64; m <<= 1) {
            sA += __shfl_xor(sA, m);
            sB += __shfl_xor(sB, m);
        }

        // Publish r(t+1) rows (paired 8B atomic store — punches through to the
        // coherence point; consumers' cached reads see it after their inv).
        if (lane == 0) {
            float bt = b_lds[t];
            float xA = fast_tanh(sA + fmaf(winA1, bt, winA0));
            float xB = fast_tanh(sB + fmaf(winB1, bt, winB0));
            float rnA = 0.5f * (r_lds[rowA] + xA);
            float rnB = 0.5f * (r_lds[rowB] + xB);
            ull pack = ((ull)__float_as_uint(rnB) << 32) | __float_as_uint(rnA);
            ull* dst = reinterpret_cast<ull*>(rbuf)
                     + (size_t)((t + 1) & 1) * (R_DIM / 2) + (rowA >> 1);
            __hip_atomic_store(dst, pack, __ATOMIC_RELAXED, AGENT);
        }

        // WG0: pred[t-1] partials (2 chunks per wave) over r(t); finalized next step.
        if (wid == 0 && t >= 1) {
            const float* wr = Wout + 2;
            float s = 0.0f;
            #pragma unroll
            for (int cc = 0; cc < 2; ++cc) {
                int c = wave * 2 + cc;
                int k = c * 256 + lane * 4;
                float2 wa = *reinterpret_cast<const float2*>(wr + k);
                float2 wb = *reinterpret_cast<const float2*>(wr + k + 2);
                float4 rv = rv4[c * 64 + lane];
                s = fmaf(wa.x, rv.x, s);
                s = fmaf(wa.y, rv.y, s);
                s = fmaf(wb.x, rv.z, s);
                s = fmaf(wb.y, rv.w, s);
            }
            #pragma unroll
            for (int m = 1; m < 64; m <<= 1) s += __shfl_xor(s, m);
            if (lane == 0) psum_lds[wave] = s;
        }

        __syncthreads();   // barrier B: drains all waves' publish stores (vmcnt(0))
        if (tid == 0)
            __hip_atomic_store(&flags[wid], t + 1, __ATOMIC_RELAXED, AGENT);
    }

    // Epilogue (WG0 only): out[T-2] from last psums; out[T-1] from r(T).
    if (wid == 0) {
        if (tid < 128) {
            const ull* fp = flags8 + tid;
            for (;;) {
                ull v = __hip_atomic_load(fp, __ATOMIC_RELAXED, AGENT);
                if ((int)(uint32)v >= T_STEPS && (int)(uint32)(v >> 32) >= T_STEPS) break;
                __builtin_amdgcn_s_sleep(1);
            }
        }
        __syncthreads();
        __builtin_amdgcn_fence(__ATOMIC_ACQUIRE, "agent");
        const float4* src4 = reinterpret_cast<const float4*>(
            rbuf + (size_t)(T_STEPS & 1) * R_DIM);
        rl4[tid]       = src4[tid];
        rl4[tid + 512] = src4[tid + 512];
        __syncthreads();
        if (tid == 0) {
            float s = ((psum_lds[0] + psum_lds[1]) + (psum_lds[2] + psum_lds[3]))
                    + ((psum_lds[4] + psum_lds[5]) + (psum_lds[6] + psum_lds[7]));
            out[T_STEPS - 2] = s + fmaf(Wout[1], b_lds[T_STEPS - 2], Wout[0]);
        }
        if (wave == 0) {
            const float* wr = Wout + 2;
            float s = 0.0f;
            #pragma unroll
            for (int c = 0; c < K_CHUNKS; ++c) {
                int k = c * 256 + lane * 4;
                float2 wa = *reinterpret_cast<const float2*>(wr + k);
                float2 wb = *reinterpret_cast<const float2*>(wr + k + 2);
                float4 rv = rv4[c * 64 + lane];
                s = fmaf(wa.x, rv.x, s);
                s = fmaf(wa.y, rv.y, s);
                s = fmaf(wb.x, rv.z, s);
                s = fmaf(wb.y, rv.w, s);
            }
            #pragma unroll
            for (int m = 1; m < 64; m <<= 1) s += __shfl_xor(s, m);
            if (lane == 0)
                out[T_STEPS - 1] = s + fmaf(Wout[1], b_lds[T_STEPS - 1], Wout[0]);
        }
    }
}

extern "C" void kernel_launch(void* const* d_in, const int* in_sizes, int n_in,
                              void* d_out, int out_size, void* d_ws, size_t ws_size,
                              hipStream_t stream) {
    (void)in_sizes; (void)n_in; (void)out_size; (void)ws_size;
    const float* batch = (const float*)d_in[0];   // (1024,1,1)
    const float* Win   = (const float*)d_in[1];   // (4096,2) row-major
    const float* W     = (const float*)d_in[2];   // (4096,4096) row-major
    const float* Wout  = (const float*)d_in[3];   // (1,4098)
    float* out  = (float*)d_out;                  // (1024,1)
    float* rbuf = (float*)d_ws;                                   // 2*4096 floats
    int*   flags = (int*)((char*)d_ws + 2 * R_DIM * sizeof(float)); // 256 ints

    // flags must start < 1 every launch (d_ws is not re-poisoned between replays).
    hipMemsetAsync(flags, 0, N_WG * sizeof(int), stream);

    // grid=256 WGs x 512 thr (8 waves = 2 waves/SIMD; 128 AGPR + ~100 VGPR fits).
    // grid == CU count => all WGs co-resident for the spin barrier.
    esn_persistent<<<dim3(N_WG), dim3(N_THR), 0, stream>>>(
        batch, Win, W, Wout, out, rbuf, flags);
}

// Round 9
// 6519.562 us; speedup vs baseline: 2.9717x; 2.9717x over previous
//
#include <hip/hip_runtime.h>

// Echo State Network, T=1024 sequential steps of r' = 0.5 r + 0.5 tanh(W r + Win u).
// Persistent kernel. W pinned in hard-named AGPRs (verified r4: VGPR_Count=128).
//
// r9 = r5 skeleton (best: 4.09 ms, deterministic absmax 6.103516e-05) with two
// serial hops removed:
//  1) barrier B + WG-wide drain replaced by per-wave certificates: lane0 waits
//     its OWN store ack (per-wave vmcnt), bumps a monotonic LDS counter; the
//     wave seeing old==8t+7 stores the WG flag. Flag launches at last-wave-done
//     instead of after an 8-wave rendezvous. 2 barriers/step instead of 3.
//  2) staging via 2x global_load_dwordx4 sc0 sc1 (16B coherence-point loads)
//     instead of 4x8B atomic loads — half the fabric transactions, same
//     staleness-safety (flag-certified stable data, no tearing possible).
// r8's lesson kept: NO fences (L2-wide inv per step = disaster). r6/r7 lessons
// kept: notification on few hot shared lines, payload read exactly once.
//
// RACE DETECTOR: absmax must read exactly 6.103516e-05. Anything else => race.
//
// d_ws layout: [0, 32768): float rbuf[2][4096] (double-buffered r, 8B-paired rows)
//              [32768, 33792): int flags[256]  (last published step per WG)

#define T_STEPS 1024
#define R_DIM   4096
#define N_WG    256
#define N_THR   512
#define ROWS_PER_WG 16
#define K_CHUNKS 16          // R_DIM / (64 lanes * 4 floats)

#define AGENT __HIP_MEMORY_SCOPE_AGENT

typedef unsigned long long ull;
typedef unsigned int uint32;
typedef __attribute__((ext_vector_type(4))) float f32x4;

__device__ __forceinline__ float fast_tanh(float x) {
    float ax = fabsf(x);
    float e  = __expf(-2.0f * ax);
    float t  = (1.0f - e) / (1.0f + e);
    return copysignf(t, x);
}

// Store one float4 into four named physical AGPRs.
#define WST4(A0, A1, A2, A3, vec)                                              \
    asm volatile("v_accvgpr_write_b32 a" #A0 ", %0\n\t"                        \
                 "v_accvgpr_write_b32 a" #A1 ", %1\n\t"                        \
                 "v_accvgpr_write_b32 a" #A2 ", %2\n\t"                        \
                 "v_accvgpr_write_b32 a" #A3 ", %3"                            \
                 :: "v"((vec).x), "v"((vec).y), "v"((vec).z), "v"((vec).w)     \
                 : "a" #A0, "a" #A1, "a" #A2, "a" #A3)

// One K-chunk of the two-row matvec: read 4+4 W values from AGPRs, FMA with rv.
#define MV2(c, A0, A1, A2, A3, B0, B1, B2, B3)                                 \
    do {                                                                       \
        float4 rv = rv4[(c) * 64 + lane];                                      \
        float w0, w1, w2, w3, u0, u1, u2, u3;                                  \
        asm volatile("v_accvgpr_read_b32 %0, a" #A0 "\n\t"                     \
                     "v_accvgpr_read_b32 %1, a" #A1 "\n\t"                     \
                     "v_accvgpr_read_b32 %2, a" #A2 "\n\t"                     \
                     "v_accvgpr_read_b32 %3, a" #A3 "\n\t"                     \
                     "v_accvgpr_read_b32 %4, a" #B0 "\n\t"                     \
                     "v_accvgpr_read_b32 %5, a" #B1 "\n\t"                     \
                     "v_accvgpr_read_b32 %6, a" #B2 "\n\t"                     \
                     "v_accvgpr_read_b32 %7, a" #B3                            \
                     : "=v"(w0), "=v"(w1), "=v"(w2), "=v"(w3),                 \
                       "=v"(u0), "=v"(u1), "=v"(u2), "=v"(u3));                \
        accA.x = fmaf(w0, rv.x, accA.x);                                       \
        accA.y = fmaf(w1, rv.y, accA.y);                                       \
        accA.z = fmaf(w2, rv.z, accA.z);                                       \
        accA.w = fmaf(w3, rv.w, accA.w);                                       \
        accB.x = fmaf(u0, rv.x, accB.x);                                       \
        accB.y = fmaf(u1, rv.y, accB.y);                                       \
        accB.z = fmaf(u2, rv.z, accB.z);                                       \
        accB.w = fmaf(u3, rv.w, accB.w);                                       \
    } while (0)

// 2x16B coherence-point loads (sc0 sc1: bypass L1/L2, served by L3 like the
// agent atomics) staged to LDS. Data is flag-certified stable => no tearing.
#define STAGE16(srcbase)                                                       \
    {                                                                          \
        const f32x4* a0 = reinterpret_cast<const f32x4*>(srcbase) + tid;       \
        const f32x4* a1 = a0 + 512;                                            \
        f32x4 s0, s1;                                                          \
        asm volatile("global_load_dwordx4 %0, %2, off sc0 sc1\n\t"             \
                     "global_load_dwordx4 %1, %3, off sc0 sc1\n\t"             \
                     "s_waitcnt vmcnt(0)"                                      \
                     : "=&v"(s0), "=&v"(s1)                                    \
                     : "v"(a0), "v"(a1)                                        \
                     : "memory");                                              \
        reinterpret_cast<f32x4*>(r_lds)[tid]       = s0;                       \
        reinterpret_cast<f32x4*>(r_lds)[tid + 512] = s1;                       \
    }

__global__ __launch_bounds__(N_THR, 2)
void esn_persistent(const float* __restrict__ batch,
                    const float* __restrict__ Win,
                    const float* __restrict__ W,
                    const float* __restrict__ Wout,
                    float* __restrict__ out,
                    float* __restrict__ rbuf,
                    int*   __restrict__ flags)
{
    __shared__ __align__(16) float r_lds[R_DIM];   // current r(t)
    __shared__ float b_lds[T_STEPS];               // input sequence
    __shared__ float psum_lds[8];                  // WG0 pred partials
    __shared__ int   done_cnt;                     // monotonic per-wave certificates

    const int tid  = threadIdx.x;
    const int wid  = blockIdx.x;
    const int wave = tid >> 6;
    const int lane = tid & 63;
    const int rowA = wid * ROWS_PER_WG + wave * 2; // this wave's two W rows
    const int rowB = rowA + 1;

    for (int i = tid; i < R_DIM; i += N_THR) r_lds[i] = 0.0f;   // r(0) = 0
    for (int i = tid; i < T_STEPS; i += N_THR) b_lds[i] = batch[i];
    if (tid == 0) done_cnt = 0;

    // Pin W rows in physical AGPRs. Lane's chunk c covers k = c*256 + lane*4.
    {
        const float4* pA = reinterpret_cast<const float4*>(W + (size_t)rowA * R_DIM);
        const float4* pB = reinterpret_cast<const float4*>(W + (size_t)rowB * R_DIM);
        float4 v;
        v = pA[ 0 * 64 + lane]; WST4(  0,   1,   2,   3, v);
        v = pA[ 1 * 64 + lane]; WST4(  4,   5,   6,   7, v);
        v = pA[ 2 * 64 + lane]; WST4(  8,   9,  10,  11, v);
        v = pA[ 3 * 64 + lane]; WST4( 12,  13,  14,  15, v);
        v = pA[ 4 * 64 + lane]; WST4( 16,  17,  18,  19, v);
        v = pA[ 5 * 64 + lane]; WST4( 20,  21,  22,  23, v);
        v = pA[ 6 * 64 + lane]; WST4( 24,  25,  26,  27, v);
        v = pA[ 7 * 64 + lane]; WST4( 28,  29,  30,  31, v);
        v = pA[ 8 * 64 + lane]; WST4( 32,  33,  34,  35, v);
        v = pA[ 9 * 64 + lane]; WST4( 36,  37,  38,  39, v);
        v = pA[10 * 64 + lane]; WST4( 40,  41,  42,  43, v);
        v = pA[11 * 64 + lane]; WST4( 44,  45,  46,  47, v);
        v = pA[12 * 64 + lane]; WST4( 48,  49,  50,  51, v);
        v = pA[13 * 64 + lane]; WST4( 52,  53,  54,  55, v);
        v = pA[14 * 64 + lane]; WST4( 56,  57,  58,  59, v);
        v = pA[15 * 64 + lane]; WST4( 60,  61,  62,  63, v);
        v = pB[ 0 * 64 + lane]; WST4( 64,  65,  66,  67, v);
        v = pB[ 1 * 64 + lane]; WST4( 68,  69,  70,  71, v);
        v = pB[ 2 * 64 + lane]; WST4( 72,  73,  74,  75, v);
        v = pB[ 3 * 64 + lane]; WST4( 76,  77,  78,  79, v);
        v = pB[ 4 * 64 + lane]; WST4( 80,  81,  82,  83, v);
        v = pB[ 5 * 64 + lane]; WST4( 84,  85,  86,  87, v);
        v = pB[ 6 * 64 + lane]; WST4( 88,  89,  90,  91, v);
        v = pB[ 7 * 64 + lane]; WST4( 92,  93,  94,  95, v);
        v = pB[ 8 * 64 + lane]; WST4( 96,  97,  98,  99, v);
        v = pB[ 9 * 64 + lane]; WST4(100, 101, 102, 103, v);
        v = pB[10 * 64 + lane]; WST4(104, 105, 106, 107, v);
        v = pB[11 * 64 + lane]; WST4(108, 109, 110, 111, v);
        v = pB[12 * 64 + lane]; WST4(112, 113, 114, 115, v);
        v = pB[13 * 64 + lane]; WST4(116, 117, 118, 119, v);
        v = pB[14 * 64 + lane]; WST4(120, 121, 122, 123, v);
        v = pB[15 * 64 + lane]; WST4(124, 125, 126, 127, v);
    }
    const float winA0 = Win[2 * rowA], winA1 = Win[2 * rowA + 1];
    const float winB0 = Win[2 * rowB], winB1 = Win[2 * rowB + 1];

    __syncthreads();

    const float4* rv4 = reinterpret_cast<const float4*>(r_lds);
    const ull* flags8 = reinterpret_cast<const ull*>(flags);

    for (int t = 0; t < T_STEPS; ++t) {
        if (t > 0) {
            // Waves 4-5 poll flag PAIRS (relaxed; 8 shared hot lines — r5 topology).
            if (tid >= 256 && tid < 256 + 128) {
                const ull* fp = flags8 + (tid - 256);
                for (;;) {
                    ull v = __hip_atomic_load(fp, __ATOMIC_RELAXED, AGENT);
                    if ((int)(uint32)v >= t && (int)(uint32)(v >> 32) >= t) break;
                    __builtin_amdgcn_s_sleep(1);
                }
            }
            __syncthreads();          // all flags >= t observed by the WG
            STAGE16(rbuf + (size_t)(t & 1) * R_DIM);
            __syncthreads();          // barrier A: r(t) staged

            // Finalize pred[t-2] from last step's psums (WG0 tid0, off crit path;
            // psum writes of step t-1 ordered before this by the two barriers above).
            if (wid == 0 && tid == 0 && t >= 2) {
                float s = ((psum_lds[0] + psum_lds[1]) + (psum_lds[2] + psum_lds[3]))
                        + ((psum_lds[4] + psum_lds[5]) + (psum_lds[6] + psum_lds[7]));
                out[t - 2] = s + fmaf(Wout[1], b_lds[t - 2], Wout[0]);
            }
        }

        // y = W r(t) for this wave's two rows (W in AGPRs, r broadcast from LDS).
        float4 accA = make_float4(0.f, 0.f, 0.f, 0.f);
        float4 accB = make_float4(0.f, 0.f, 0.f, 0.f);
        MV2( 0,   0,   1,   2,   3,  64,  65,  66,  67);
        MV2( 1,   4,   5,   6,   7,  68,  69,  70,  71);
        MV2( 2,   8,   9,  10,  11,  72,  73,  74,  75);
        MV2( 3,  12,  13,  14,  15,  76,  77,  78,  79);
        MV2( 4,  16,  17,  18,  19,  80,  81,  82,  83);
        MV2( 5,  20,  21,  22,  23,  84,  85,  86,  87);
        MV2( 6,  24,  25,  26,  27,  88,  89,  90,  91);
        MV2( 7,  28,  29,  30,  31,  92,  93,  94,  95);
        MV2( 8,  32,  33,  34,  35,  96,  97,  98,  99);
        MV2( 9,  36,  37,  38,  39, 100, 101, 102, 103);
        MV2(10,  40,  41,  42,  43, 104, 105, 106, 107);
        MV2(11,  44,  45,  46,  47, 108, 109, 110, 111);
        MV2(12,  48,  49,  50,  51, 112, 113, 114, 115);
        MV2(13,  52,  53,  54,  55, 116, 117, 118, 119);
        MV2(14,  56,  57,  58,  59, 120, 121, 122, 123);
        MV2(15,  60,  61,  62,  63, 124, 125, 126, 127);

        float sA = (accA.x + accA.y) + (accA.z + accA.w);
        float sB = (accB.x + accB.y) + (accB.z + accB.w);
        #pragma unroll
        for (int m = 1; m < 64; m <<= 1) {
            sA += __shfl_xor(sA, m);
            sB += __shfl_xor(sB, m);
        }

        // Publish r(t+1) rows (paired 8B atomic store). Safe vs ping-pong
        // overwrite: we are past the poll of step t (all flags >= t), so every
        // WG finished reading r(t-1) from this buffer.
        if (lane == 0) {
            float bt = b_lds[t];
            float xA = fast_tanh(sA + fmaf(winA1, bt, winA0));
            float xB = fast_tanh(sB + fmaf(winB1, bt, winB0));
            float rnA = 0.5f * (r_lds[rowA] + xA);
            float rnB = 0.5f * (r_lds[rowB] + xB);
            ull pack = ((ull)__float_as_uint(rnB) << 32) | __float_as_uint(rnA);
            ull* dst = reinterpret_cast<ull*>(rbuf)
                     + (size_t)((t + 1) & 1) * (R_DIM / 2) + (rowA >> 1);
            __hip_atomic_store(dst, pack, __ATOMIC_RELAXED, AGENT);
        }

        // WG0: pred[t-1] partials over r(t) — BEFORE this wave's certificate so
        // its r_lds reads are covered by the own-WG flag ordering.
        if (wid == 0 && t >= 1) {
            const float* wr = Wout + 2;
            float s = 0.0f;
            #pragma unroll
            for (int cc = 0; cc < 2; ++cc) {
                int c = wave * 2 + cc;
                int k = c * 256 + lane * 4;
                float2 wa = *reinterpret_cast<const float2*>(wr + k);
                float2 wb = *reinterpret_cast<const float2*>(wr + k + 2);
                float4 rv = rv4[c * 64 + lane];
                s = fmaf(wa.x, rv.x, s);
                s = fmaf(wa.y, rv.y, s);
                s = fmaf(wb.x, rv.z, s);
                s = fmaf(wb.y, rv.w, s);
            }
            #pragma unroll
            for (int m = 1; m < 64; m <<= 1) s += __shfl_xor(s, m);
            if (lane == 0) psum_lds[wave] = s;
        }

        // Per-wave certificate: wait own store ack (per-wave vmcnt), bump the
        // monotonic counter; the wave seeing old==8t+7 launches the WG flag.
        if (lane == 0) {
            asm volatile("s_waitcnt vmcnt(0)" ::: "memory");
            __builtin_amdgcn_sched_barrier(0);
            int old = atomicAdd(&done_cnt, 1);
            if (old == 8 * t + 7)
                __hip_atomic_store(&flags[wid], t + 1, __ATOMIC_RELAXED, AGENT);
        }
    }

    // Epilogue (WG0 only): out[T-2] from last psums; out[T-1] from r(T).
    if (wid == 0) {
        if (tid < 128) {
            const ull* fp = flags8 + tid;
            for (;;) {
                ull v = __hip_atomic_load(fp, __ATOMIC_RELAXED, AGENT);
                if ((int)(uint32)v >= T_STEPS && (int)(uint32)(v >> 32) >= T_STEPS) break;
                __builtin_amdgcn_s_sleep(1);
            }
        }
        __syncthreads();
        STAGE16(rbuf + (size_t)(T_STEPS & 1) * R_DIM);
        __syncthreads();
        if (tid == 0) {
            float s = ((psum_lds[0] + psum_lds[1]) + (psum_lds[2] + psum_lds[3]))
                    + ((psum_lds[4] + psum_lds[5]) + (psum_lds[6] + psum_lds[7]));
            out[T_STEPS - 2] = s + fmaf(Wout[1], b_lds[T_STEPS - 2], Wout[0]);
        }
        if (wave == 0) {
            const float* wr = Wout + 2;
            float s = 0.0f;
            #pragma unroll
            for (int c = 0; c < K_CHUNKS; ++c) {
                int k = c * 256 + lane * 4;
                float2 wa = *reinterpret_cast<const float2*>(wr + k);
                float2 wb = *reinterpret_cast<const float2*>(wr + k + 2);
                float4 rv = rv4[c * 64 + lane];
                s = fmaf(wa.x, rv.x, s);
                s = fmaf(wa.y, rv.y, s);
                s = fmaf(wb.x, rv.z, s);
                s = fmaf(wb.y, rv.w, s);
            }
            #pragma unroll
            for (int m = 1; m < 64; m <<= 1) s += __shfl_xor(s, m);
            if (lane == 0)
                out[T_STEPS - 1] = s + fmaf(Wout[1], b_lds[T_STEPS - 1], Wout[0]);
        }
    }
}

extern "C" void kernel_launch(void* const* d_in, const int* in_sizes, int n_in,
                              void* d_out, int out_size, void* d_ws, size_t ws_size,
                              hipStream_t stream) {
    (void)in_sizes; (void)n_in; (void)out_size; (void)ws_size;
    const float* batch = (const float*)d_in[0];   // (1024,1,1)
    const float* Win   = (const float*)d_in[1];   // (4096,2) row-major
    const float* W     = (const float*)d_in[2];   // (4096,4096) row-major
    const float* Wout  = (const float*)d_in[3];   // (1,4098)
    float* out  = (float*)d_out;                  // (1024,1)
    float* rbuf = (float*)d_ws;                                   // 2*4096 floats
    int*   flags = (int*)((char*)d_ws + 2 * R_DIM * sizeof(float)); // 256 ints

    // flags must start < 1 every launch (d_ws is not re-poisoned between replays).
    hipMemsetAsync(flags, 0, N_WG * sizeof(int), stream);

    // grid=256 WGs x 512 thr (8 waves = 2 waves/SIMD; 128 AGPR + ~100 VGPR fits).
    // grid == CU count => all WGs co-resident for the spin barrier.
    esn_persistent<<<dim3(N_WG), dim3(N_THR), 0, stream>>>(
        batch, Win, W, Wout, out, rbuf, flags);
}

// Round 10
// 4870.856 us; speedup vs baseline: 3.9775x; 1.3385x over previous
//
#include <hip/hip_runtime.h>

// Echo State Network, T=1024 sequential steps of r' = 0.5 r + 0.5 tanh(W r + Win u).
// Persistent kernel. W pinned in hard-named AGPRs (verified r4: VGPR_Count=128).
//
// r10 = EXACT r5 sync skeleton (best proven: 4.09 ms, absmax 6.103516e-05):
//   waves 4-5 poll 128 flag-pairs -> barrier -> stage -> barrier A -> matvec ->
//   paired 8B atomic publish -> [psum] -> barrier B (vmcnt drain) -> tid0 flag.
// Changes vs r5 (both precedented clean in r6/r8/r9):
//  1) pred = psum-split: r5 had WG0 wave0 do the FULL 4096-dot serially before
//     its matvec => WG0 was the device straggler every step (~0.3-0.5 us/step
//     on the global critical path). Now each WG0 wave adds 2 chunks to
//     psum_lds before barrier B; tid0 finalizes out[t-2] after the next
//     staging barrier — entirely off the inter-WG path.
//  2) staging: 4x8B atomic loads batched into registers BEFORE any LDS store
//     (kills any load->ds_write->load serialization; r7-staging form).
// r9's certificate + sc0sc1 loads REVERTED (6.5 ms). r8's fence REVERTED
// (19 ms). r6's poll-the-data REVERTED (8 ms). r7's all-thread poll REVERTED.
//
// RACE DETECTOR: absmax must read exactly 6.103516e-05. Anything else => race.
//
// d_ws layout: [0, 32768): float rbuf[2][4096] (double-buffered r, 8B-paired rows)
//              [32768, 33792): int flags[256]  (last published step per WG)

#define T_STEPS 1024
#define R_DIM   4096
#define N_WG    256
#define N_THR   512
#define ROWS_PER_WG 16
#define K_CHUNKS 16          // R_DIM / (64 lanes * 4 floats)

#define AGENT __HIP_MEMORY_SCOPE_AGENT

typedef unsigned long long ull;
typedef unsigned int uint32;

__device__ __forceinline__ float fast_tanh(float x) {
    float ax = fabsf(x);
    float e  = __expf(-2.0f * ax);
    float t  = (1.0f - e) / (1.0f + e);
    return copysignf(t, x);
}

// Store one float4 into four named physical AGPRs.
#define WST4(A0, A1, A2, A3, vec)                                              \
    asm volatile("v_accvgpr_write_b32 a" #A0 ", %0\n\t"                        \
                 "v_accvgpr_write_b32 a" #A1 ", %1\n\t"                        \
                 "v_accvgpr_write_b32 a" #A2 ", %2\n\t"                        \
                 "v_accvgpr_write_b32 a" #A3 ", %3"                            \
                 :: "v"((vec).x), "v"((vec).y), "v"((vec).z), "v"((vec).w)     \
                 : "a" #A0, "a" #A1, "a" #A2, "a" #A3)

// One K-chunk of the two-row matvec: read 4+4 W values from AGPRs, FMA with rv.
#define MV2(c, A0, A1, A2, A3, B0, B1, B2, B3)                                 \
    do {                                                                       \
        float4 rv = rv4[(c) * 64 + lane];                                      \
        float w0, w1, w2, w3, u0, u1, u2, u3;                                  \
        asm volatile("v_accvgpr_read_b32 %0, a" #A0 "\n\t"                     \
                     "v_accvgpr_read_b32 %1, a" #A1 "\n\t"                     \
                     "v_accvgpr_read_b32 %2, a" #A2 "\n\t"                     \
                     "v_accvgpr_read_b32 %3, a" #A3 "\n\t"                     \
                     "v_accvgpr_read_b32 %4, a" #B0 "\n\t"                     \
                     "v_accvgpr_read_b32 %5, a" #B1 "\n\t"                     \
                     "v_accvgpr_read_b32 %6, a" #B2 "\n\t"                     \
                     "v_accvgpr_read_b32 %7, a" #B3                            \
                     : "=v"(w0), "=v"(w1), "=v"(w2), "=v"(w3),                 \
                       "=v"(u0), "=v"(u1), "=v"(u2), "=v"(u3));                \
        accA.x = fmaf(w0, rv.x, accA.x);                                       \
        accA.y = fmaf(w1, rv.y, accA.y);                                       \
        accA.z = fmaf(w2, rv.z, accA.z);                                       \
        accA.w = fmaf(w3, rv.w, accA.w);                                       \
        accB.x = fmaf(u0, rv.x, accB.x);                                       \
        accB.y = fmaf(u1, rv.y, accB.y);                                       \
        accB.z = fmaf(u2, rv.z, accB.z);                                       \
        accB.w = fmaf(u3, rv.w, accB.w);                                       \
    } while (0)

__global__ __launch_bounds__(N_THR, 2)
void esn_persistent(const float* __restrict__ batch,
                    const float* __restrict__ Win,
                    const float* __restrict__ W,
                    const float* __restrict__ Wout,
                    float* __restrict__ out,
                    float* __restrict__ rbuf,
                    int*   __restrict__ flags)
{
    __shared__ __align__(16) float r_lds[R_DIM];   // current r(t)
    __shared__ float b_lds[T_STEPS];               // input sequence
    __shared__ float psum_lds[8];                  // WG0 pred partials

    const int tid  = threadIdx.x;
    const int wid  = blockIdx.x;
    const int wave = tid >> 6;
    const int lane = tid & 63;
    const int rowA = wid * ROWS_PER_WG + wave * 2; // this wave's two W rows
    const int rowB = rowA + 1;

    for (int i = tid; i < R_DIM; i += N_THR) r_lds[i] = 0.0f;   // r(0) = 0
    for (int i = tid; i < T_STEPS; i += N_THR) b_lds[i] = batch[i];

    // Pin W rows in physical AGPRs. Lane's chunk c covers k = c*256 + lane*4.
    {
        const float4* pA = reinterpret_cast<const float4*>(W + (size_t)rowA * R_DIM);
        const float4* pB = reinterpret_cast<const float4*>(W + (size_t)rowB * R_DIM);
        float4 v;
        v = pA[ 0 * 64 + lane]; WST4(  0,   1,   2,   3, v);
        v = pA[ 1 * 64 + lane]; WST4(  4,   5,   6,   7, v);
        v = pA[ 2 * 64 + lane]; WST4(  8,   9,  10,  11, v);
        v = pA[ 3 * 64 + lane]; WST4( 12,  13,  14,  15, v);
        v = pA[ 4 * 64 + lane]; WST4( 16,  17,  18,  19, v);
        v = pA[ 5 * 64 + lane]; WST4( 20,  21,  22,  23, v);
        v = pA[ 6 * 64 + lane]; WST4( 24,  25,  26,  27, v);
        v = pA[ 7 * 64 + lane]; WST4( 28,  29,  30,  31, v);
        v = pA[ 8 * 64 + lane]; WST4( 32,  33,  34,  35, v);
        v = pA[ 9 * 64 + lane]; WST4( 36,  37,  38,  39, v);
        v = pA[10 * 64 + lane]; WST4( 40,  41,  42,  43, v);
        v = pA[11 * 64 + lane]; WST4( 44,  45,  46,  47, v);
        v = pA[12 * 64 + lane]; WST4( 48,  49,  50,  51, v);
        v = pA[13 * 64 + lane]; WST4( 52,  53,  54,  55, v);
        v = pA[14 * 64 + lane]; WST4( 56,  57,  58,  59, v);
        v = pA[15 * 64 + lane]; WST4( 60,  61,  62,  63, v);
        v = pB[ 0 * 64 + lane]; WST4( 64,  65,  66,  67, v);
        v = pB[ 1 * 64 + lane]; WST4( 68,  69,  70,  71, v);
        v = pB[ 2 * 64 + lane]; WST4( 72,  73,  74,  75, v);
        v = pB[ 3 * 64 + lane]; WST4( 76,  77,  78,  79, v);
        v = pB[ 4 * 64 + lane]; WST4( 80,  81,  82,  83, v);
        v = pB[ 5 * 64 + lane]; WST4( 84,  85,  86,  87, v);
        v = pB[ 6 * 64 + lane]; WST4( 88,  89,  90,  91, v);
        v = pB[ 7 * 64 + lane]; WST4( 92,  93,  94,  95, v);
        v = pB[ 8 * 64 + lane]; WST4( 96,  97,  98,  99, v);
        v = pB[ 9 * 64 + lane]; WST4(100, 101, 102, 103, v);
        v = pB[10 * 64 + lane]; WST4(104, 105, 106, 107, v);
        v = pB[11 * 64 + lane]; WST4(108, 109, 110, 111, v);
        v = pB[12 * 64 + lane]; WST4(112, 113, 114, 115, v);
        v = pB[13 * 64 + lane]; WST4(116, 117, 118, 119, v);
        v = pB[14 * 64 + lane]; WST4(120, 121, 122, 123, v);
        v = pB[15 * 64 + lane]; WST4(124, 125, 126, 127, v);
    }
    const float winA0 = Win[2 * rowA], winA1 = Win[2 * rowA + 1];
    const float winB0 = Win[2 * rowB], winB1 = Win[2 * rowB + 1];

    __syncthreads();

    const float4* rv4 = reinterpret_cast<const float4*>(r_lds);
    ull* r_lds8 = reinterpret_cast<ull*>(r_lds);
    const ull* flags8 = reinterpret_cast<const ull*>(flags);

    for (int t = 0; t < T_STEPS; ++t) {
        if (t > 0) {
            // Waves 4-5 poll flag PAIRS (relaxed; 8 shared hot lines — r5 topology).
            if (tid >= 256 && tid < 256 + 128) {
                const ull* fp = flags8 + (tid - 256);
                for (;;) {
                    ull v = __hip_atomic_load(fp, __ATOMIC_RELAXED, AGENT);
                    if ((int)(uint32)v >= t && (int)(uint32)(v >> 32) >= t) break;
                    __builtin_amdgcn_s_sleep(1);
                }
            }
            __syncthreads();
            // Stage rbuf[t&1] -> LDS: all 4 8B atomic loads into registers
            // FIRST (MLP), then LDS stores (r7-staging form, r5 semantics).
            const ull* src8 = reinterpret_cast<const ull*>(rbuf) + (size_t)(t & 1) * (R_DIM / 2);
            ull u0 = __hip_atomic_load(src8 + tid + 0 * 512, __ATOMIC_RELAXED, AGENT);
            ull u1 = __hip_atomic_load(src8 + tid + 1 * 512, __ATOMIC_RELAXED, AGENT);
            ull u2 = __hip_atomic_load(src8 + tid + 2 * 512, __ATOMIC_RELAXED, AGENT);
            ull u3 = __hip_atomic_load(src8 + tid + 3 * 512, __ATOMIC_RELAXED, AGENT);
            r_lds8[tid + 0 * 512] = u0;
            r_lds8[tid + 1 * 512] = u1;
            r_lds8[tid + 2 * 512] = u2;
            r_lds8[tid + 3 * 512] = u3;
            __syncthreads();   // barrier A: r(t) staged

            // Finalize pred[t-2] from last step's psums (WG0 tid0, off the
            // inter-WG critical path; psum writes are 2 barriers back).
            if (wid == 0 && tid == 0 && t >= 2) {
                float s = ((psum_lds[0] + psum_lds[1]) + (psum_lds[2] + psum_lds[3]))
                        + ((psum_lds[4] + psum_lds[5]) + (psum_lds[6] + psum_lds[7]));
                out[t - 2] = s + fmaf(Wout[1], b_lds[t - 2], Wout[0]);
            }
        }

        // y = W r(t) for this wave's two rows (W in AGPRs, r broadcast from LDS).
        float4 accA = make_float4(0.f, 0.f, 0.f, 0.f);
        float4 accB = make_float4(0.f, 0.f, 0.f, 0.f);
        MV2( 0,   0,   1,   2,   3,  64,  65,  66,  67);
        MV2( 1,   4,   5,   6,   7,  68,  69,  70,  71);
        MV2( 2,   8,   9,  10,  11,  72,  73,  74,  75);
        MV2( 3,  12,  13,  14,  15,  76,  77,  78,  79);
        MV2( 4,  16,  17,  18,  19,  80,  81,  82,  83);
        MV2( 5,  20,  21,  22,  23,  84,  85,  86,  87);
        MV2( 6,  24,  25,  26,  27,  88,  89,  90,  91);
        MV2( 7,  28,  29,  30,  31,  92,  93,  94,  95);
        MV2( 8,  32,  33,  34,  35,  96,  97,  98,  99);
        MV2( 9,  36,  37,  38,  39, 100, 101, 102, 103);
        MV2(10,  40,  41,  42,  43, 104, 105, 106, 107);
        MV2(11,  44,  45,  46,  47, 108, 109, 110, 111);
        MV2(12,  48,  49,  50,  51, 112, 113, 114, 115);
        MV2(13,  52,  53,  54,  55, 116, 117, 118, 119);
        MV2(14,  56,  57,  58,  59, 120, 121, 122, 123);
        MV2(15,  60,  61,  62,  63, 124, 125, 126, 127);

        float sA = (accA.x + accA.y) + (accA.z + accA.w);
        float sB = (accB.x + accB.y) + (accB.z + accB.w);
        #pragma unroll
        for (int m = 1; m < 64; m <<= 1) {
            sA += __shfl_xor(sA, m);
            sB += __shfl_xor(sB, m);
        }

        // Publish r(t+1) rows (paired 8B atomic store). Safe vs ping-pong
        // overwrite: past the poll of step t (all flags >= t), so every WG
        // finished reading r(t-1) from this buffer.
        if (lane == 0) {
            float bt = b_lds[t];
            float xA = fast_tanh(sA + fmaf(winA1, bt, winA0));
            float xB = fast_tanh(sB + fmaf(winB1, bt, winB0));
            float rnA = 0.5f * (r_lds[rowA] + xA);
            float rnB = 0.5f * (r_lds[rowB] + xB);
            ull pack = ((ull)__float_as_uint(rnB) << 32) | __float_as_uint(rnA);
            ull* dst = reinterpret_cast<ull*>(rbuf)
                     + (size_t)((t + 1) & 1) * (R_DIM / 2) + (rowA >> 1);
            __hip_atomic_store(dst, pack, __ATOMIC_RELAXED, AGENT);
        }

        // WG0: pred[t-1] partials (2 chunks/wave) over r(t); finalized at t+1.
        if (wid == 0 && t >= 1) {
            const float* wr = Wout + 2;
            float s = 0.0f;
            #pragma unroll
            for (int cc = 0; cc < 2; ++cc) {
                int c = wave * 2 + cc;
                int k = c * 256 + lane * 4;
                float2 wa = *reinterpret_cast<const float2*>(wr + k);
                float2 wb = *reinterpret_cast<const float2*>(wr + k + 2);
                float4 rv = rv4[c * 64 + lane];
                s = fmaf(wa.x, rv.x, s);
                s = fmaf(wa.y, rv.y, s);
                s = fmaf(wb.x, rv.z, s);
                s = fmaf(wb.y, rv.w, s);
            }
            #pragma unroll
            for (int m = 1; m < 64; m <<= 1) s += __shfl_xor(s, m);
            if (lane == 0) psum_lds[wave] = s;
        }

        __syncthreads();   // barrier B: drains all waves' publish stores (vmcnt(0))
        if (tid == 0)
            __hip_atomic_store(&flags[wid], t + 1, __ATOMIC_RELAXED, AGENT);
    }

    // Epilogue (WG0 only): out[T-2] from last psums; out[T-1] from r(T).
    if (wid == 0) {
        if (tid < 128) {
            const ull* fp = flags8 + tid;
            for (;;) {
                ull v = __hip_atomic_load(fp, __ATOMIC_RELAXED, AGENT);
                if ((int)(uint32)v >= T_STEPS && (int)(uint32)(v >> 32) >= T_STEPS) break;
                __builtin_amdgcn_s_sleep(1);
            }
        }
        __syncthreads();
        const ull* src8 = reinterpret_cast<const ull*>(rbuf) + (size_t)(T_STEPS & 1) * (R_DIM / 2);
        ull u0 = __hip_atomic_load(src8 + tid + 0 * 512, __ATOMIC_RELAXED, AGENT);
        ull u1 = __hip_atomic_load(src8 + tid + 1 * 512, __ATOMIC_RELAXED, AGENT);
        ull u2 = __hip_atomic_load(src8 + tid + 2 * 512, __ATOMIC_RELAXED, AGENT);
        ull u3 = __hip_atomic_load(src8 + tid + 3 * 512, __ATOMIC_RELAXED, AGENT);
        r_lds8[tid + 0 * 512] = u0;
        r_lds8[tid + 1 * 512] = u1;
        r_lds8[tid + 2 * 512] = u2;
        r_lds8[tid + 3 * 512] = u3;
        __syncthreads();
        if (tid == 0) {
            float s = ((psum_lds[0] + psum_lds[1]) + (psum_lds[2] + psum_lds[3]))
                    + ((psum_lds[4] + psum_lds[5]) + (psum_lds[6] + psum_lds[7]));
            out[T_STEPS - 2] = s + fmaf(Wout[1], b_lds[T_STEPS - 2], Wout[0]);
        }
        if (wave == 0) {
            const float* wr = Wout + 2;
            float s = 0.0f;
            #pragma unroll
            for (int c = 0; c < K_CHUNKS; ++c) {
                int k = c * 256 + lane * 4;
                float2 wa = *reinterpret_cast<const float2*>(wr + k);
                float2 wb = *reinterpret_cast<const float2*>(wr + k + 2);
                float4 rv = rv4[c * 64 + lane];
                s = fmaf(wa.x, rv.x, s);
                s = fmaf(wa.y, rv.y, s);
                s = fmaf(wb.x, rv.z, s);
                s = fmaf(wb.y, rv.w, s);
            }
            #pragma unroll
            for (int m = 1; m < 64; m <<= 1) s += __shfl_xor(s, m);
            if (lane == 0)
                out[T_STEPS - 1] = s + fmaf(Wout[1], b_lds[T_STEPS - 1], Wout[0]);
        }
    }
}

extern "C" void kernel_launch(void* const* d_in, const int* in_sizes, int n_in,
                              void* d_out, int out_size, void* d_ws, size_t ws_size,
                              hipStream_t stream) {
    (void)in_sizes; (void)n_in; (void)out_size; (void)ws_size;
    const float* batch = (const float*)d_in[0];   // (1024,1,1)
    const float* Win   = (const float*)d_in[1];   // (4096,2) row-major
    const float* W     = (const float*)d_in[2];   // (4096,4096) row-major
    const float* Wout  = (const float*)d_in[3];   // (1,4098)
    float* out  = (float*)d_out;                  // (1024,1)
    float* rbuf = (float*)d_ws;                                   // 2*4096 floats
    int*   flags = (int*)((char*)d_ws + 2 * R_DIM * sizeof(float)); // 256 ints

    // flags must start < 1 every launch (d_ws is not re-poisoned between replays).
    hipMemsetAsync(flags, 0, N_WG * sizeof(int), stream);

    // grid=256 WGs x 512 thr (8 waves = 2 waves/SIMD; 128 AGPR + ~100 VGPR fits).
    // grid == CU count => all WGs co-resident for the spin barrier.
    esn_persistent<<<dim3(N_WG), dim3(N_THR), 0, stream>>>(
        batch, Win, W, Wout, out, rbuf, flags);
}

// Round 11
// 4184.506 us; speedup vs baseline: 4.6299x; 1.1640x over previous
//
#include <hip/hip_runtime.h>

// Echo State Network, T=1024 sequential steps of r' = 0.5 r + 0.5 tanh(W r + Win u).
// Persistent kernel. W pinned in hard-named AGPRs (verified r4: VGPR_Count=128).
//
// r11 = BYTE-EXACT r5 sync skeleton (best proven: 4.09 ms, absmax 6.103516e-05):
//   waves 4-5 poll 128 flag-pairs -> barrier -> stage (interleaved 4x8B loop) ->
//   barrier A -> matvec -> paired 8B atomic publish -> barrier B -> tid0 flag.
// ONE change vs r5: pred moved into the flag-propagation SHADOW, rotated
// across WGs. r5 computed pred on WG0 wave0 between barrier A and matvec =>
// WG0's flag ~200 ns late EVERY step, gating all 256 WGs (r10 proved spreading
// it before barrier B is no better — still pre-flag). Now WG ((t-1)&255)
// wave0 computes the full Wout.r(t) dot AFTER its flag store: overlaps the
// 600-900 ns flag-propagation + poll window (pure wait for this WG), reads
// r_lds which stays stable until next staging (wave0 gates that barrier), and
// each WG only does the dot ~4x/1024 steps. Zero new sync structure.
// Reverted experiments: r6 poll-the-data (8ms), r7 all-thread poll (6ms),
// r8 acquire-fence (19ms), r9 certificate+sc-loads (6.5ms), r10 bundle (4.9ms).
//
// RACE DETECTOR: absmax must read exactly 6.103516e-05. Anything else => race.
//
// d_ws layout: [0, 32768): float rbuf[2][4096] (double-buffered r, 8B-paired rows)
//              [32768, 33792): int flags[256]  (last published step per WG)

#define T_STEPS 1024
#define R_DIM   4096
#define N_WG    256
#define N_THR   512
#define ROWS_PER_WG 16
#define K_CHUNKS 16          // R_DIM / (64 lanes * 4 floats)

#define AGENT __HIP_MEMORY_SCOPE_AGENT

typedef unsigned long long ull;
typedef unsigned int uint32;

__device__ __forceinline__ float fast_tanh(float x) {
    float ax = fabsf(x);
    float e  = __expf(-2.0f * ax);
    float t  = (1.0f - e) / (1.0f + e);
    return copysignf(t, x);
}

// Store one float4 into four named physical AGPRs.
#define WST4(A0, A1, A2, A3, vec)                                              \
    asm volatile("v_accvgpr_write_b32 a" #A0 ", %0\n\t"                        \
                 "v_accvgpr_write_b32 a" #A1 ", %1\n\t"                        \
                 "v_accvgpr_write_b32 a" #A2 ", %2\n\t"                        \
                 "v_accvgpr_write_b32 a" #A3 ", %3"                            \
                 :: "v"((vec).x), "v"((vec).y), "v"((vec).z), "v"((vec).w)     \
                 : "a" #A0, "a" #A1, "a" #A2, "a" #A3)

// One K-chunk of the two-row matvec: read 4+4 W values from AGPRs, FMA with rv.
#define MV2(c, A0, A1, A2, A3, B0, B1, B2, B3)                                 \
    do {                                                                       \
        float4 rv = rv4[(c) * 64 + lane];                                      \
        float w0, w1, w2, w3, u0, u1, u2, u3;                                  \
        asm volatile("v_accvgpr_read_b32 %0, a" #A0 "\n\t"                     \
                     "v_accvgpr_read_b32 %1, a" #A1 "\n\t"                     \
                     "v_accvgpr_read_b32 %2, a" #A2 "\n\t"                     \
                     "v_accvgpr_read_b32 %3, a" #A3 "\n\t"                     \
                     "v_accvgpr_read_b32 %4, a" #B0 "\n\t"                     \
                     "v_accvgpr_read_b32 %5, a" #B1 "\n\t"                     \
                     "v_accvgpr_read_b32 %6, a" #B2 "\n\t"                     \
                     "v_accvgpr_read_b32 %7, a" #B3                            \
                     : "=v"(w0), "=v"(w1), "=v"(w2), "=v"(w3),                 \
                       "=v"(u0), "=v"(u1), "=v"(u2), "=v"(u3));                \
        accA.x = fmaf(w0, rv.x, accA.x);                                       \
        accA.y = fmaf(w1, rv.y, accA.y);                                       \
        accA.z = fmaf(w2, rv.z, accA.z);                                       \
        accA.w = fmaf(w3, rv.w, accA.w);                                       \
        accB.x = fmaf(u0, rv.x, accB.x);                                       \
        accB.y = fmaf(u1, rv.y, accB.y);                                       \
        accB.z = fmaf(u2, rv.z, accB.z);                                       \
        accB.w = fmaf(u3, rv.w, accB.w);                                       \
    } while (0)

__global__ __launch_bounds__(N_THR, 2)
void esn_persistent(const float* __restrict__ batch,
                    const float* __restrict__ Win,
                    const float* __restrict__ W,
                    const float* __restrict__ Wout,
                    float* __restrict__ out,
                    float* __restrict__ rbuf,
                    int*   __restrict__ flags)
{
    __shared__ __align__(16) float r_lds[R_DIM];   // current r(t)
    __shared__ float b_lds[T_STEPS];               // input sequence

    const int tid  = threadIdx.x;
    const int wid  = blockIdx.x;
    const int wave = tid >> 6;
    const int lane = tid & 63;
    const int rowA = wid * ROWS_PER_WG + wave * 2; // this wave's two W rows
    const int rowB = rowA + 1;

    for (int i = tid; i < R_DIM; i += N_THR) r_lds[i] = 0.0f;   // r(0) = 0
    for (int i = tid; i < T_STEPS; i += N_THR) b_lds[i] = batch[i];

    // Pin W rows in physical AGPRs. Lane's chunk c covers k = c*256 + lane*4.
    {
        const float4* pA = reinterpret_cast<const float4*>(W + (size_t)rowA * R_DIM);
        const float4* pB = reinterpret_cast<const float4*>(W + (size_t)rowB * R_DIM);
        float4 v;
        v = pA[ 0 * 64 + lane]; WST4(  0,   1,   2,   3, v);
        v = pA[ 1 * 64 + lane]; WST4(  4,   5,   6,   7, v);
        v = pA[ 2 * 64 + lane]; WST4(  8,   9,  10,  11, v);
        v = pA[ 3 * 64 + lane]; WST4( 12,  13,  14,  15, v);
        v = pA[ 4 * 64 + lane]; WST4( 16,  17,  18,  19, v);
        v = pA[ 5 * 64 + lane]; WST4( 20,  21,  22,  23, v);
        v = pA[ 6 * 64 + lane]; WST4( 24,  25,  26,  27, v);
        v = pA[ 7 * 64 + lane]; WST4( 28,  29,  30,  31, v);
        v = pA[ 8 * 64 + lane]; WST4( 32,  33,  34,  35, v);
        v = pA[ 9 * 64 + lane]; WST4( 36,  37,  38,  39, v);
        v = pA[10 * 64 + lane]; WST4( 40,  41,  42,  43, v);
        v = pA[11 * 64 + lane]; WST4( 44,  45,  46,  47, v);
        v = pA[12 * 64 + lane]; WST4( 48,  49,  50,  51, v);
        v = pA[13 * 64 + lane]; WST4( 52,  53,  54,  55, v);
        v = pA[14 * 64 + lane]; WST4( 56,  57,  58,  59, v);
        v = pA[15 * 64 + lane]; WST4( 60,  61,  62,  63, v);
        v = pB[ 0 * 64 + lane]; WST4( 64,  65,  66,  67, v);
        v = pB[ 1 * 64 + lane]; WST4( 68,  69,  70,  71, v);
        v = pB[ 2 * 64 + lane]; WST4( 72,  73,  74,  75, v);
        v = pB[ 3 * 64 + lane]; WST4( 76,  77,  78,  79, v);
        v = pB[ 4 * 64 + lane]; WST4( 80,  81,  82,  83, v);
        v = pB[ 5 * 64 + lane]; WST4( 84,  85,  86,  87, v);
        v = pB[ 6 * 64 + lane]; WST4( 88,  89,  90,  91, v);
        v = pB[ 7 * 64 + lane]; WST4( 92,  93,  94,  95, v);
        v = pB[ 8 * 64 + lane]; WST4( 96,  97,  98,  99, v);
        v = pB[ 9 * 64 + lane]; WST4(100, 101, 102, 103, v);
        v = pB[10 * 64 + lane]; WST4(104, 105, 106, 107, v);
        v = pB[11 * 64 + lane]; WST4(108, 109, 110, 111, v);
        v = pB[12 * 64 + lane]; WST4(112, 113, 114, 115, v);
        v = pB[13 * 64 + lane]; WST4(116, 117, 118, 119, v);
        v = pB[14 * 64 + lane]; WST4(120, 121, 122, 123, v);
        v = pB[15 * 64 + lane]; WST4(124, 125, 126, 127, v);
    }
    const float winA0 = Win[2 * rowA], winA1 = Win[2 * rowA + 1];
    const float winB0 = Win[2 * rowB], winB1 = Win[2 * rowB + 1];

    __syncthreads();

    const float4* rv4 = reinterpret_cast<const float4*>(r_lds);
    ull* r_lds8 = reinterpret_cast<ull*>(r_lds);
    const ull* flags8 = reinterpret_cast<const ull*>(flags);

    for (int t = 0; t < T_STEPS; ++t) {
        if (t > 0) {
            // Waves 4-5 poll flag PAIRS (relaxed; 8 shared hot lines — r5 topology).
            if (tid >= 256 && tid < 256 + 128) {
                const ull* fp = flags8 + (tid - 256);
                for (;;) {
                    ull v = __hip_atomic_load(fp, __ATOMIC_RELAXED, AGENT);
                    if ((int)(uint32)v >= t && (int)(uint32)(v >> 32) >= t) break;
                    __builtin_amdgcn_s_sleep(1);
                }
            }
            __syncthreads();
            // Stage rbuf[t&1] -> LDS as 8-B relaxed loads (4/thread — r5 form).
            const ull* src8 = reinterpret_cast<const ull*>(rbuf) + (size_t)(t & 1) * (R_DIM / 2);
            #pragma unroll
            for (int j = 0; j < 4; ++j) {
                int i = tid + j * 512;
                r_lds8[i] = __hip_atomic_load(src8 + i, __ATOMIC_RELAXED, AGENT);
            }
            __syncthreads();   // barrier A: r(t) staged
        }

        // y = W r(t) for this wave's two rows (W in AGPRs, r broadcast from LDS).
        float4 accA = make_float4(0.f, 0.f, 0.f, 0.f);
        float4 accB = make_float4(0.f, 0.f, 0.f, 0.f);
        MV2( 0,   0,   1,   2,   3,  64,  65,  66,  67);
        MV2( 1,   4,   5,   6,   7,  68,  69,  70,  71);
        MV2( 2,   8,   9,  10,  11,  72,  73,  74,  75);
        MV2( 3,  12,  13,  14,  15,  76,  77,  78,  79);
        MV2( 4,  16,  17,  18,  19,  80,  81,  82,  83);
        MV2( 5,  20,  21,  22,  23,  84,  85,  86,  87);
        MV2( 6,  24,  25,  26,  27,  88,  89,  90,  91);
        MV2( 7,  28,  29,  30,  31,  92,  93,  94,  95);
        MV2( 8,  32,  33,  34,  35,  96,  97,  98,  99);
        MV2( 9,  36,  37,  38,  39, 100, 101, 102, 103);
        MV2(10,  40,  41,  42,  43, 104, 105, 106, 107);
        MV2(11,  44,  45,  46,  47, 108, 109, 110, 111);
        MV2(12,  48,  49,  50,  51, 112, 113, 114, 115);
        MV2(13,  52,  53,  54,  55, 116, 117, 118, 119);
        MV2(14,  56,  57,  58,  59, 120, 121, 122, 123);
        MV2(15,  60,  61,  62,  63, 124, 125, 126, 127);

        float sA = (accA.x + accA.y) + (accA.z + accA.w);
        float sB = (accB.x + accB.y) + (accB.z + accB.w);
        #pragma unroll
        for (int m = 1; m < 64; m <<= 1) {
            sA += __shfl_xor(sA, m);
            sB += __shfl_xor(sB, m);
        }

        // Publish r(t+1) rows (paired 8B atomic store). Safe vs ping-pong
        // overwrite: past the poll of step t (all flags >= t), so every WG
        // finished reading r(t-1) from this buffer.
        if (lane == 0) {
            float bt = b_lds[t];
            float xA = fast_tanh(sA + fmaf(winA1, bt, winA0));
            float xB = fast_tanh(sB + fmaf(winB1, bt, winB0));
            float rnA = 0.5f * (r_lds[rowA] + xA);
            float rnB = 0.5f * (r_lds[rowB] + xB);
            ull pack = ((ull)__float_as_uint(rnB) << 32) | __float_as_uint(rnA);
            ull* dst = reinterpret_cast<ull*>(rbuf)
                     + (size_t)((t + 1) & 1) * (R_DIM / 2) + (rowA >> 1);
            __hip_atomic_store(dst, pack, __ATOMIC_RELAXED, AGENT);
        }

        __syncthreads();   // barrier B: drains all waves' publish stores (vmcnt(0))
        if (tid == 0)
            __hip_atomic_store(&flags[wid], t + 1, __ATOMIC_RELAXED, AGENT);

        // Rotated pred in the flag-propagation SHADOW: WG ((t-1)&255) wave0
        // computes out[t-1] = Wout0 + Wout1*b[t-1] + Wout[2:].r(t) AFTER the
        // flag store. Overlaps the ~600-900ns flag->poll window; r_lds stays
        // valid (wave0 gates the next staging barrier); ~4 dots per WG total.
        if (t >= 1 && wave == 0 && wid == ((t - 1) & 255)) {
            const float* wr = Wout + 2;
            float s = 0.0f;
            #pragma unroll
            for (int c = 0; c < K_CHUNKS; ++c) {
                int k = c * 256 + lane * 4;
                float2 wa = *reinterpret_cast<const float2*>(wr + k);
                float2 wb = *reinterpret_cast<const float2*>(wr + k + 2);
                float4 rv = rv4[c * 64 + lane];
                s = fmaf(wa.x, rv.x, s);
                s = fmaf(wa.y, rv.y, s);
                s = fmaf(wb.x, rv.z, s);
                s = fmaf(wb.y, rv.w, s);
            }
            #pragma unroll
            for (int m = 1; m < 64; m <<= 1) s += __shfl_xor(s, m);
            if (lane == 0)
                out[t - 1] = s + fmaf(Wout[1], b_lds[t - 1], Wout[0]);
        }
    }

    // Epilogue (WG0 only): out[T-1] from r(T).
    if (wid == 0) {
        if (tid < 128) {
            const ull* fp = flags8 + tid;
            for (;;) {
                ull v = __hip_atomic_load(fp, __ATOMIC_RELAXED, AGENT);
                if ((int)(uint32)v >= T_STEPS && (int)(uint32)(v >> 32) >= T_STEPS) break;
                __builtin_amdgcn_s_sleep(1);
            }
        }
        __syncthreads();
        const ull* src8 = reinterpret_cast<const ull*>(rbuf) + (size_t)(T_STEPS & 1) * (R_DIM / 2);
        #pragma unroll
        for (int j = 0; j < 4; ++j) {
            int i = tid + j * 512;
            r_lds8[i] = __hip_atomic_load(src8 + i, __ATOMIC_RELAXED, AGENT);
        }
        __syncthreads();
        if (wave == 0) {
            const float* wr = Wout + 2;
            float s = 0.0f;
            #pragma unroll
            for (int c = 0; c < K_CHUNKS; ++c) {
                int k = c * 256 + lane * 4;
                float2 wa = *reinterpret_cast<const float2*>(wr + k);
                float2 wb = *reinterpret_cast<const float2*>(wr + k + 2);
                float4 rv = rv4[c * 64 + lane];
                s = fmaf(wa.x, rv.x, s);
                s = fmaf(wa.y, rv.y, s);
                s = fmaf(wb.x, rv.z, s);
                s = fmaf(wb.y, rv.w, s);
            }
            #pragma unroll
            for (int m = 1; m < 64; m <<= 1) s += __shfl_xor(s, m);
            if (lane == 0)
                out[T_STEPS - 1] = s + fmaf(Wout[1], b_lds[T_STEPS - 1], Wout[0]);
        }
    }
}

extern "C" void kernel_launch(void* const* d_in, const int* in_sizes, int n_in,
                              void* d_out, int out_size, void* d_ws, size_t ws_size,
                              hipStream_t stream) {
    (void)in_sizes; (void)n_in; (void)out_size; (void)ws_size;
    const float* batch = (const float*)d_in[0];   // (1024,1,1)
    const float* Win   = (const float*)d_in[1];   // (4096,2) row-major
    const float* W     = (const float*)d_in[2];   // (4096,4096) row-major
    const float* Wout  = (const float*)d_in[3];   // (1,4098)
    float* out  = (float*)d_out;                  // (1024,1)
    float* rbuf = (float*)d_ws;                                   // 2*4096 floats
    int*   flags = (int*)((char*)d_ws + 2 * R_DIM * sizeof(float)); // 256 ints

    // flags must start < 1 every launch (d_ws is not re-poisoned between replays).
    hipMemsetAsync(flags, 0, N_WG * sizeof(int), stream);

    // grid=256 WGs x 512 thr (8 waves = 2 waves/SIMD; 128 AGPR + ~100 VGPR fits).
    // grid == CU count => all WGs co-resident for the spin barrier.
    esn_persistent<<<dim3(N_WG), dim3(N_THR), 0, stream>>>(
        batch, Win, W, Wout, out, rbuf, flags);
}